// Round 4
// baseline (247.952 us; speedup 1.0000x reference)
//
#include <hip/hip_runtime.h>

#define NPTS 131072
#define MNBR 34
#define KP 15
#define CIN 32
#define COUT 64
#define INV_INFL 25.0f          // 1 / POINT_INFLUENCE(0.04)
#define BN_EPS 1e-5f
#define NEG_SLOPE 0.2f
#define PPB 16                  // points per block (2 waves x 8)
#define NBLK (NPTS / PPB)       // 8192 conv blocks
#define NBIN 2048               // stat bins (4 blocks per bin)

typedef unsigned short u16;
typedef unsigned int u32;
typedef short short8 __attribute__((ext_vector_type(8)));   // 8 bf16 (4 VGPRs)
typedef float f32x4 __attribute__((ext_vector_type(4)));

static __device__ __forceinline__ u16 f2bf(float f) {       // RNE
    u32 x = __float_as_uint(f);
    x += 0x7fffu + ((x >> 16) & 1u);
    return (u16)(x >> 16);
}
static __device__ __forceinline__ u32 pk2bf(float lo, float hi) {  // round-half-up pack
    u32 a = __float_as_uint(lo) + 0x8000u;
    u32 b = __float_as_uint(hi) + 0x8000u;
    return (a >> 16) | (b & 0xffff0000u);
}

// ws layout (bytes) — total 9.13 MB (under proven 10.6 MB budget)
#define WS_WT   0u              // u16[64*480]        = 61440
#define WS_SCSH 65536u          // f32[128]
#define WS_SP   131072u         // f32[64*2048]       = 524288   (atomic bins)
#define WS_QP   655360u         // f32[64*2048]       = 524288   (contiguous after SP)
#define WS_FB   1179648u        // u16[(NPTS+1)*32]   = 8388672  bf16 feats + zero shadow row

// prep: WT transpose, FB bf16 table (+shadow row), zero stat bins
__global__ __launch_bounds__(256) void prep(const float* __restrict__ Wg,
                                            const float* __restrict__ feats,
                                            u16* __restrict__ WT, u32* __restrict__ FBu,
                                            float* __restrict__ SpQp) {
    int b = blockIdx.x;
    if (b < 120) {
        int tid2 = b * 256 + threadIdx.x;        // < 30720
        int i = tid2 >> 6, d = tid2 & 63;        // i = k*32+c (coalesced read)
        WT[d * 480 + i] = f2bf(Wg[tid2]);
    } else if (b < 120 + 8193) {
        int g = (b - 120) * 256 + threadIdx.x;   // u32 index into FB
        if (g < ((NPTS + 1) * CIN) / 2) {
            int e = g * 2;
            u32 v = 0;
            if (e < NPTS * CIN)
                v = (u32)f2bf(feats[e]) | ((u32)f2bf(feats[e + 1]) << 16);
            FBu[g] = v;                          // row NPTS -> zeros (shadow)
        }
    } else {
        int idx = (b - 8313) * 256 + threadIdx.x;
        if (idx < 2 * 64 * NBIN) SpQp[idx] = 0.f;   // zero Sp and Qp (contiguous)
    }
}

__global__ __launch_bounds__(128, 3) void kpconv_conv(
    const float* __restrict__ xyz, const int* __restrict__ nbr,
    const u16* __restrict__ FB, const u16* __restrict__ WT,
    const float* __restrict__ kpts, float* __restrict__ out,
    float* __restrict__ Sp, float* __restrict__ Qp)
{
    // wf: 16 rows x 512 bf16; 16B-unit u of row r at phys (u ^ (r&7))   [R3-verified]
    __shared__ u32 wf[PPB * 256];          // 16 KB
    // nbt: per-wave [word w=0..15][m=0..63], dword addr = w*68 + m (4-dword row pad)
    __shared__ u32 nbt[2][16 * 68];        // 8704 B
    // wk: per-wave w[k][m] bf16, 8-u16 unit (m>>3) xor-swizzled by k      [R3-verified]
    __shared__ u16 wk[2][16 * 64];         // 4 KB
    // total 29184 B -> 5 blocks/CU

    const int tid = threadIdx.x, lane = tid & 63, wave = tid >> 6;
    const int q = lane >> 4, t = lane & 15;

    // uniform kernel-point constants: d^2 = (o . a_k + c_k) + |o|^2, a = -2*kp
    float ax[16], ay[16], az[16], ck[16];
    #pragma unroll
    for (int k = 0; k < KP; ++k) {
        float kx = kpts[3 * k], ky = kpts[3 * k + 1], kz = kpts[3 * k + 2];
        ax[k] = -2.f * kx; ay[k] = -2.f * ky; az[k] = -2.f * kz;
        ck[k] = fmaf(kx, kx, fmaf(ky, ky, kz * kz));
    }
    ax[15] = 0.f; ay[15] = 0.f; az[15] = 0.f; ck[15] = 1e12f;   // k=15 pad -> w=0

    u32* nb = nbt[wave];
    u16* wl = wk[wave];
    const int pbase = blockIdx.x * PPB + wave * 8;

    // ---------------- pipelined prologue: nbr 2 ahead, gathers 1 ahead
    int ci = NPTS;                                   // current point's neighbor idx
    if (lane < MNBR) ci = nbr[(size_t)pbase * MNBR + lane];
    if ((unsigned)ci > (unsigned)NPTS) ci = NPTS;
    int nn = NPTS;                                   // next point's neighbor idx
    if (lane < MNBR) nn = nbr[(size_t)(pbase + 1) * MNBR + lane];
    if ((unsigned)nn > (unsigned)NPTS) nn = NPTS;

    int il = ci < NPTS ? ci : 0;
    float cnx = xyz[3 * il], cny = xyz[3 * il + 1], cnz = xyz[3 * il + 2];
    const uint4* fr = (const uint4*)(FB + (size_t)ci * CIN);
    uint4 cf0 = fr[0], cf1 = fr[1], cf2 = fr[2], cf3 = fr[3];

    for (int p = 0; p < 8; ++p) {
        // issue nbr for p+2
        int nn2 = NPTS;
        if (p < 6) {
            if (lane < MNBR) nn2 = nbr[(size_t)(pbase + p + 2) * MNBR + lane];
            if ((unsigned)nn2 > (unsigned)NPTS) nn2 = NPTS;
        }
        // issue gathers for p+1 (nn loaded an iteration ago)
        float nx1 = 0.f, ny1 = 0.f, nz1 = 0.f;
        uint4 nf0 = {}, nf1 = {}, nf2 = {}, nf3 = {};
        if (p < 7) {
            int il1 = nn < NPTS ? nn : 0;
            nx1 = xyz[3 * il1]; ny1 = xyz[3 * il1 + 1]; nz1 = xyz[3 * il1 + 2];
            const uint4* fr1 = (const uint4*)(FB + (size_t)nn * CIN);
            nf0 = fr1[0]; nf1 = fr1[1]; nf2 = fr1[2]; nf3 = fr1[3];
        }

        // ---- current point p
        const int n = pbase + p;                     // uniform -> scalar loads
        const float qx = xyz[3 * n], qy = xyz[3 * n + 1], qz = xyz[3 * n + 2];
        float ox = cnx - qx, oy = cny - qy, oz = cnz - qz;
        if (ci >= NPTS) { ox = 1e6f; oy = 0.f; oz = 0.f; }    // shadow/idle lane -> w=0
        const float oo = fmaf(ox, ox, fmaf(oy, oy, oz * oz));

        // w column (all 16 k) for m = lane -> swizzled wk
        #pragma unroll
        for (int k = 0; k < 16; ++k) {
            float d2 = fmaf(ox, ax[k], fmaf(oy, ay[k], fmaf(oz, az[k], ck[k]))) + oo;
            float d = __builtin_amdgcn_sqrtf(d2);                  // d2<0 tiny -> NaN -> max gives 0
            float w = fmaxf(0.f, fmaf(d, -INV_INFL, 1.f));
            wl[k * 64 + ((((lane >> 3) ^ (k & 7))) << 3) + (lane & 7)] =
                (u16)((__float_as_uint(w) + 0x8000u) >> 16);
        }

        // neighbor feature row -> transposed nbt: lane m writes word w at w*68+m (2-way free)
        {
            u32 fd[16] = {cf0.x, cf0.y, cf0.z, cf0.w, cf1.x, cf1.y, cf1.z, cf1.w,
                          cf2.x, cf2.y, cf2.z, cf2.w, cf3.x, cf3.y, cf3.z, cf3.w};
            #pragma unroll
            for (int w16 = 0; w16 < 16; ++w16)
                nb[w16 * 68 + lane] = fd[w16];
        }

        // rotate pipeline stages
        cnx = nx1; cny = ny1; cnz = nz1;
        cf0 = nf0; cf1 = nf1; cf2 = nf2; cf3 = nf3;
        ci = nn; nn = nn2;

        // A-frags: k-row t, m-chunks q and 4+q (compiler inserts lgkmcnt)
        short8 a0 = *(const short8*)&wl[t * 64 + (((q) ^ (t & 7)) << 3)];
        short8 a1 = *(const short8*)&wl[t * 64 + (((4 + q) ^ (t & 7)) << 3)];

        // B-frags: 4 x b128 from nbt, 8-lanes-per-bank-group optimal
        uint4 b0 = *(const uint4*)&nb[t * 68 + 8 * q];        // m = 8q+0..3
        uint4 b1 = *(const uint4*)&nb[t * 68 + 8 * q + 4];    // m = 8q+4..7
        uint4 b2 = *(const uint4*)&nb[t * 68 + 8 * q + 32];   // m = 32+8q+0..3
        uint4 b3 = *(const uint4*)&nb[t * 68 + 8 * q + 36];
        union { short8 v; u32 d[4]; } e0, o0, e1, o1;
        {
            u32 r0[8] = {b0.x, b0.y, b0.z, b0.w, b1.x, b1.y, b1.z, b1.w};
            u32 r1[8] = {b2.x, b2.y, b2.z, b2.w, b3.x, b3.y, b3.z, b3.w};
            #pragma unroll
            for (int i2 = 0; i2 < 4; ++i2) {
                u32 a = r0[2 * i2], b = r0[2 * i2 + 1];
                e0.d[i2] = (a & 0xffffu) | (b << 16);
                o0.d[i2] = (a >> 16) | (b & 0xffff0000u);
                a = r1[2 * i2]; b = r1[2 * i2 + 1];
                e1.d[i2] = (a & 0xffffu) | (b << 16);
                o1.d[i2] = (a >> 16) | (b & 0xffff0000u);
            }
        }

        f32x4 c0 = {0.f, 0.f, 0.f, 0.f}, c1 = {0.f, 0.f, 0.f, 0.f};
        c0 = __builtin_amdgcn_mfma_f32_16x16x32_bf16(a0, e0.v, c0, 0, 0, 0);
        c0 = __builtin_amdgcn_mfma_f32_16x16x32_bf16(a1, e1.v, c0, 0, 0, 0);
        c1 = __builtin_amdgcn_mfma_f32_16x16x32_bf16(a0, o0.v, c1, 0, 0, 0);
        c1 = __builtin_amdgcn_mfma_f32_16x16x32_bf16(a1, o1.v, c1, 0, 0, 0);

        // D (col=t holds ch 2t/2t+1, row ko=q*4+r) -> swizzled wf row (R3-verified)
        const int row = wave * 8 + p;
        #pragma unroll
        for (int r = 0; r < 4; ++r) {
            int ko = q * 4 + r;
            u32 pk = pk2bf(c0[r], c1[r]);
            int unit = ko * 4 + (t >> 2);
            wf[row * 256 + ((unit ^ (row & 7)) << 2) + (t & 3)] = pk;
        }
    }
    __syncthreads();

    // -------- Phase B: OUT[16x64] = wf[16x480] @ W[480x64]; wave does 2 col-tiles
    const int wcol0 = (wave * 2 + 0) * 16 + t;
    const int wcol1 = (wave * 2 + 1) * 16 + t;
    f32x4 A0 = {0.f, 0.f, 0.f, 0.f}, A1 = {0.f, 0.f, 0.f, 0.f};
    const u16* wt0 = WT + wcol0 * 480 + q * 8;
    const u16* wt1 = WT + wcol1 * 480 + q * 8;
    #pragma unroll
    for (int ks = 0; ks < KP; ++ks) {
        const int u = ks * 4 + q;
        short8 a  = *(const short8*)&wf[t * 256 + ((u ^ (t & 7)) << 2)];
        short8 bb0 = *(const short8*)(wt0 + ks * 32);
        short8 bb1 = *(const short8*)(wt1 + ks * 32);
        A0 = __builtin_amdgcn_mfma_f32_16x16x32_bf16(a, bb0, A0, 0, 0, 0);
        A1 = __builtin_amdgcn_mfma_f32_16x16x32_bf16(a, bb1, A1, 0, 0, 0);
    }
    const int base = blockIdx.x * PPB;
    float s0 = 0.f, q0 = 0.f, s1 = 0.f, q1 = 0.f;
    #pragma unroll
    for (int r = 0; r < 4; ++r) {
        float v0 = A0[r], v1 = A1[r];
        out[(base + q * 4 + r) * COUT + wcol0] = v0;
        out[(base + q * 4 + r) * COUT + wcol1] = v1;
        s0 += v0; q0 = fmaf(v0, v0, q0);
        s1 += v1; q1 = fmaf(v1, v1, q1);
    }
    s0 += __shfl_xor(s0, 16, 64); s0 += __shfl_xor(s0, 32, 64);
    q0 += __shfl_xor(q0, 16, 64); q0 += __shfl_xor(q0, 32, 64);
    s1 += __shfl_xor(s1, 16, 64); s1 += __shfl_xor(s1, 32, 64);
    q1 += __shfl_xor(q1, 16, 64); q1 += __shfl_xor(q1, 32, 64);
    if (q == 0) {
        const int bin = blockIdx.x >> 2;
        atomicAdd(&Sp[wcol0 * NBIN + bin], s0);
        atomicAdd(&Qp[wcol0 * NBIN + bin], q0);
        atomicAdd(&Sp[wcol1 * NBIN + bin], s1);
        atomicAdd(&Qp[wcol1 * NBIN + bin], q1);
    }
}

// 64 blocks: block = channel; reduce bins -> scale/shift
__global__ __launch_bounds__(256) void bn_reduce(
    const float* __restrict__ Sp, const float* __restrict__ Qp,
    const float* __restrict__ gamma, const float* __restrict__ beta,
    float* __restrict__ scsh)
{
    const int ch = blockIdx.x;
    const float4* S4 = (const float4*)(Sp + ch * NBIN);
    const float4* Q4 = (const float4*)(Qp + ch * NBIN);
    float s = 0.f, qq = 0.f;
    #pragma unroll
    for (int r = 0; r < NBIN / 4 / 256; ++r) {           // 2 iters
        float4 a = S4[threadIdx.x + 256 * r]; s  += a.x + a.y + a.z + a.w;
        float4 b = Q4[threadIdx.x + 256 * r]; qq += b.x + b.y + b.z + b.w;
    }
    #pragma unroll
    for (int off = 1; off < 64; off <<= 1) {
        s += __shfl_xor(s, off, 64); qq += __shfl_xor(qq, off, 64);
    }
    __shared__ float red[8];
    const int w = threadIdx.x >> 6;
    if ((threadIdx.x & 63) == 0) { red[w * 2] = s; red[w * 2 + 1] = qq; }
    __syncthreads();
    if (threadIdx.x == 0) {
        s  = red[0] + red[2] + red[4] + red[6];
        qq = red[1] + red[3] + red[5] + red[7];
        float mean = s * (1.0f / NPTS);
        float var  = qq * (1.0f / NPTS) - mean * mean;
        float sc = gamma[ch] * rsqrtf(var + BN_EPS);
        scsh[ch] = sc;
        scsh[64 + ch] = beta[ch] - mean * sc;
    }
}

__global__ __launch_bounds__(256) void bn_apply(
    float* __restrict__ out, const float* __restrict__ scsh)
{
    __shared__ float sc[64], sh[64];
    const int tid = threadIdx.x;
    if (tid < 64) { sc[tid] = scsh[tid]; sh[tid] = scsh[64 + tid]; }
    __syncthreads();
    const int gid = blockIdx.x * 256 + tid;          // 4 f32 per thread
    float4 v = ((const float4*)out)[gid];
    const int c0 = (gid * 4) & 63;
    float y0 = fmaf(v.x, sc[c0 + 0], sh[c0 + 0]);
    float y1 = fmaf(v.y, sc[c0 + 1], sh[c0 + 1]);
    float y2 = fmaf(v.z, sc[c0 + 2], sh[c0 + 2]);
    float y3 = fmaf(v.w, sc[c0 + 3], sh[c0 + 3]);
    float4 w;
    w.x = fmaxf(y0, NEG_SLOPE * y0);
    w.y = fmaxf(y1, NEG_SLOPE * y1);
    w.z = fmaxf(y2, NEG_SLOPE * y2);
    w.w = fmaxf(y3, NEG_SLOPE * y3);
    ((float4*)out)[gid] = w;
}

extern "C" void kernel_launch(void* const* d_in, const int* in_sizes, int n_in,
                              void* d_out, int out_size, void* d_ws, size_t ws_size,
                              hipStream_t stream) {
    (void)in_sizes; (void)n_in; (void)out_size; (void)ws_size;
    const float* xyz   = (const float*)d_in[0];
    const float* feats = (const float*)d_in[1];
    const int*   nbr   = (const int*)d_in[2];
    const float* Wg    = (const float*)d_in[3];
    const float* kpts  = (const float*)d_in[4];
    const float* gamma = (const float*)d_in[5];
    const float* beta  = (const float*)d_in[6];
    float* out = (float*)d_out;
    char* ws = (char*)d_ws;
    u16*   WT   = (u16*)(ws + WS_WT);
    float* scsh = (float*)(ws + WS_SCSH);
    float* Sp   = (float*)(ws + WS_SP);
    float* Qp   = (float*)(ws + WS_QP);
    u16*   FB   = (u16*)(ws + WS_FB);

    prep<<<dim3(120 + 8193 + 1024), dim3(256), 0, stream>>>(Wg, feats, WT, (u32*)FB, Sp);
    kpconv_conv<<<dim3(NBLK), dim3(128), 0, stream>>>(xyz, nbr, FB, WT, kpts, out, Sp, Qp);
    bn_reduce<<<dim3(64), dim3(256), 0, stream>>>(Sp, Qp, gamma, beta, scsh);
    bn_apply<<<dim3((NPTS * COUT) / (256 * 4)), dim3(256), 0, stream>>>(out, scsh);
}

// Round 5
// 219.883 us; speedup vs baseline: 1.1277x; 1.1277x over previous
//
#include <hip/hip_runtime.h>

#define NPTS 131072
#define MNBR 34
#define KP 15
#define CIN 32
#define COUT 64
#define INV_INFL 25.0f          // 1 / POINT_INFLUENCE(0.04)
#define BN_EPS 1e-5f
#define NEG_SLOPE 0.2f
#define PPB 16                  // points per block (2 waves x 8)
#define NBLK (NPTS / PPB)       // 8192 conv blocks
#define NBIN 512                // stat bins (16 blocks per bin)

typedef unsigned short u16;
typedef unsigned int u32;
typedef short short8 __attribute__((ext_vector_type(8)));   // 8 bf16 (4 VGPRs)
typedef float f32x4 __attribute__((ext_vector_type(4)));

static __device__ __forceinline__ u16 f2bf(float f) {       // RNE
    u32 x = __float_as_uint(f);
    x += 0x7fffu + ((x >> 16) & 1u);
    return (u16)(x >> 16);
}
static __device__ __forceinline__ u32 pk2bf(float lo, float hi) {  // round-half-up pack
    u32 a = __float_as_uint(lo) + 0x8000u;
    u32 b = __float_as_uint(hi) + 0x8000u;
    return (a >> 16) | (b & 0xffff0000u);
}

// ws layout (bytes) — total 10.38 MB (< R3's proven 10.62 MB)
#define WS_WT   0u              // u16[64*480]          = 61440
#define WS_SCSH 65536u          // f32[128]
#define WS_SP   131072u         // f32[64*512]          = 131072 (atomic bins)
#define WS_QP   262144u         // f32[64*512]          = 131072 (contiguous after SP)
#define WS_XY   393216u         // float4[NPTS+1]       = 2097168 (xyz padded + shadow row)
#define WS_FB   2490624u        // u16[(NPTS+1)*32]     = 8388672 bf16 feats + zero shadow row

// prep: WT transpose, XY padded xyz table, FB bf16 table, zero stat bins
__global__ __launch_bounds__(256) void prep(const float* __restrict__ Wg,
                                            const float* __restrict__ feats,
                                            const float* __restrict__ xyz,
                                            u16* __restrict__ WT, float4* __restrict__ XY,
                                            u32* __restrict__ FBu, float* __restrict__ SpQp) {
    int b = blockIdx.x;
    if (b < 120) {
        int i2 = b * 256 + threadIdx.x;          // < 30720
        WT[(i2 & 63) * 480 + (i2 >> 6)] = f2bf(Wg[i2]);
    } else if (b < 633) {
        int r = (b - 120) * 256 + threadIdx.x;
        if (r <= NPTS) {
            float4 v;
            if (r < NPTS) v = make_float4(xyz[3 * r], xyz[3 * r + 1], xyz[3 * r + 2], 0.f);
            else          v = make_float4(1e6f, 1e6f, 1e6f, 0.f);   // shadow -> w = 0
            XY[r] = v;
        }
    } else if (b < 8826) {
        int g = (b - 633) * 256 + threadIdx.x;   // u32 index into FB
        if (g < ((NPTS + 1) * CIN) / 2) {
            int e = g * 2;
            u32 v = 0;
            if (e < NPTS * CIN)
                v = (u32)f2bf(feats[e]) | ((u32)f2bf(feats[e + 1]) << 16);
            FBu[g] = v;                          // row NPTS -> zeros (shadow)
        }
    } else {
        SpQp[(b - 8826) * 256 + threadIdx.x] = 0.f;   // 256 blocks x 256 = 65536 = Sp|Qp
    }
}

__global__ __launch_bounds__(128, 3) void kpconv_conv(
    const float* __restrict__ xyz, const int* __restrict__ nbr,
    const float4* __restrict__ XY, const u32* __restrict__ FBu,
    const u16* __restrict__ WT, const float* __restrict__ kpts,
    float* __restrict__ out, float* __restrict__ Sp, float* __restrict__ Qp)
{
    // wf: 16 rows x 512 bf16; 16B-unit u of row r at phys (u ^ (r&7))   [R3-verified]
    __shared__ u32 wf[PPB * 256];            // 16 KB
    // offs: per-wave double-buffered (ox,oy,oz,|o|^2) records; slot m at
    // phys (m&~7)|((m^(m>>3))&7)  -> j-indexed b128 broadcast reads conflict-free
    __shared__ float4 offs4[2][2][64];       // 4 KB
    __shared__ u32 idxs[2][2][64];           // 2 KB       (total 22.5 KB -> 7 blocks/CU)

    const int tid = threadIdx.x, lane = tid & 63, wave = tid >> 6;
    const int q = lane >> 4, t = lane & 15;
    const int pbase = blockIdx.x * PPB + wave * 8;

    // per-lane kernel-point constants (k == t only): d^2 = (o.a_t + c_t) + |o|^2
    float axt = 0.f, ayt = 0.f, azt = 0.f, ckt = 1e30f;   // t==15 pad -> w=0
    if (t < KP) {
        float kx = kpts[3 * t], ky = kpts[3 * t + 1], kz = kpts[3 * t + 2];
        axt = -2.f * kx; ayt = -2.f * ky; azt = -2.f * kz;
        ckt = fmaf(kx, kx, fmaf(ky, ky, kz * kz));
    }
    const int wslot = (lane & ~7) | ((lane ^ (lane >> 3)) & 7);

    auto ldnbr = [&](int pp) {
        int v = NPTS;
        if (lane < MNBR) v = nbr[(size_t)(pbase + pp) * MNBR + lane];
        if ((u32)v > (u32)NPTS) v = NPTS;
        return v;
    };

    u32 fbC[8], fbN[8] = {0,0,0,0,0,0,0,0};
    u32 d32C = 0, d33C = 0, d32N = 0, d33N = 0;

    // ---------------- prologue: fully stage point 0, prefetch idx(1),idx(2), pos(1)
    int ixA = ldnbr(0);
    int ix1 = ldnbr(1);
    int ix2 = ldnbr(2);
    float4 pn0 = XY[ixA];
    float4 pn1 = XY[ix1];
    {
        const int n1 = pbase;
        float qx = xyz[3 * n1], qy = xyz[3 * n1 + 1], qz = xyz[3 * n1 + 2];
        float ox = pn0.x - qx, oy = pn0.y - qy, oz = pn0.z - qz;
        offs4[wave][0][wslot] = make_float4(ox, oy, oz, fmaf(ox, ox, fmaf(oy, oy, oz * oz)));
        idxs[wave][0][lane] = (u32)ixA;
        #pragma unroll
        for (int j = 0; j < 8; ++j) {
            u32 row = idxs[wave][0][q * 8 + j];
            fbC[j] = FBu[(size_t)row * 16 + t];
        }
        int r32 = __builtin_amdgcn_readlane(ixA, 32);
        int r33 = __builtin_amdgcn_readlane(ixA, 33);
        d32C = FBu[(size_t)r32 * 16 + t];
        d33C = FBu[(size_t)r33 * 16 + t];
    }

    for (int p = 0; p < 8; ++p) {
        // (a) nbr for p+3
        int ixN = NPTS;
        if (p < 5) ixN = ldnbr(p + 3);
        // (b) neighbor positions for p+2
        float4 pn2 = make_float4(1e6f, 1e6f, 1e6f, 0.f);
        if (p < 6) pn2 = XY[ix2];
        // (c) stage p+1: offsets + idx to LDS, then issue its FB loads
        if (p < 7) {
            const int n1 = pbase + p + 1;
            float qx = xyz[3 * n1], qy = xyz[3 * n1 + 1], qz = xyz[3 * n1 + 2];
            float ox = pn1.x - qx, oy = pn1.y - qy, oz = pn1.z - qz;
            const int bb = (p + 1) & 1;
            offs4[wave][bb][wslot] = make_float4(ox, oy, oz, fmaf(ox, ox, fmaf(oy, oy, oz * oz)));
            idxs[wave][bb][lane] = (u32)ix1;
            #pragma unroll
            for (int j = 0; j < 8; ++j) {
                u32 row = idxs[wave][bb][q * 8 + j];
                fbN[j] = FBu[(size_t)row * 16 + t];
            }
            int r32 = __builtin_amdgcn_readlane(ix1, 32);
            int r33 = __builtin_amdgcn_readlane(ix1, 33);
            d32N = FBu[(size_t)r32 * 16 + t];
            d33N = FBu[(size_t)r33 * 16 + t];
        }

        // (d) compute point p — frags straight from regs/LDS
        const float4* ob = &offs4[wave][p & 1][0];
        float wj[8];
        #pragma unroll
        for (int j = 0; j < 8; ++j) {
            float4 o = ob[q * 8 + (j ^ q)];
            float d2 = fmaf(o.x, axt, fmaf(o.y, ayt, fmaf(o.z, azt, ckt))) + o.w;
            float dd = __builtin_amdgcn_sqrtf(d2);       // d2<0 tiny -> NaN -> fmax gives 0
            wj[j] = fmaxf(0.f, fmaf(dd, -INV_INFL, 1.f));
        }
        union { short8 v; u32 d[4]; } a1, a2, e1, o1, e2, o2;
        #pragma unroll
        for (int i = 0; i < 4; ++i) a1.d[i] = pk2bf(wj[2 * i], wj[2 * i + 1]);
        {   // K-step 2 covers real rows m=32,33 only (A/B nonzero just in q==0, j<2)
            float4 oA = ob[36], oB = ob[37];             // phys slots of m=32,33
            float dA = __builtin_amdgcn_sqrtf(fmaf(oA.x, axt, fmaf(oA.y, ayt, fmaf(oA.z, azt, ckt))) + oA.w);
            float dB = __builtin_amdgcn_sqrtf(fmaf(oB.x, axt, fmaf(oB.y, ayt, fmaf(oB.z, azt, ckt))) + oB.w);
            float wA = fmaxf(0.f, fmaf(dA, -INV_INFL, 1.f));
            float wB = fmaxf(0.f, fmaf(dB, -INV_INFL, 1.f));
            a2.d[0] = (q == 0) ? pk2bf(wA, wB) : 0u;
            a2.d[1] = 0; a2.d[2] = 0; a2.d[3] = 0;
        }
        #pragma unroll
        for (int i = 0; i < 4; ++i) {                    // even/odd channel split
            u32 aa = fbC[2 * i], bb2 = fbC[2 * i + 1];
            e1.d[i] = (aa & 0xffffu) | (bb2 << 16);
            o1.d[i] = (aa >> 16) | (bb2 & 0xffff0000u);
        }
        {
            u32 lo = (d32C & 0xffffu) | (d33C << 16);
            u32 hi = (d32C >> 16) | (d33C & 0xffff0000u);
            e2.d[0] = (q == 0) ? lo : 0u;  e2.d[1] = 0; e2.d[2] = 0; e2.d[3] = 0;
            o2.d[0] = (q == 0) ? hi : 0u;  o2.d[1] = 0; o2.d[2] = 0; o2.d[3] = 0;
        }
        f32x4 c0 = {0.f, 0.f, 0.f, 0.f}, c1 = {0.f, 0.f, 0.f, 0.f};
        c0 = __builtin_amdgcn_mfma_f32_16x16x32_bf16(a1.v, e1.v, c0, 0, 0, 0);
        c0 = __builtin_amdgcn_mfma_f32_16x16x32_bf16(a2.v, e2.v, c0, 0, 0, 0);
        c1 = __builtin_amdgcn_mfma_f32_16x16x32_bf16(a1.v, o1.v, c1, 0, 0, 0);
        c1 = __builtin_amdgcn_mfma_f32_16x16x32_bf16(a2.v, o2.v, c1, 0, 0, 0);

        // D (col=t -> ch 2t/2t+1, row ko=q*4+r) -> swizzled wf row   [R3-verified]
        const int row = wave * 8 + p;
        #pragma unroll
        for (int r = 0; r < 4; ++r) {
            int ko = q * 4 + r;
            u32 pk = pk2bf(c0[r], c1[r]);
            int unit = ko * 4 + (t >> 2);
            wf[row * 256 + ((unit ^ (row & 7)) << 2) + (t & 3)] = pk;
        }

        // rotate pipeline
        #pragma unroll
        for (int j = 0; j < 8; ++j) fbC[j] = fbN[j];
        d32C = d32N; d33C = d33N;
        pn1 = pn2; ix1 = ix2; ix2 = ixN;
    }
    __syncthreads();

    // -------- Phase B (R4-verified): OUT[16x64] = wf[16x480] @ W[480x64]; 2 col-tiles/wave
    const int wcol0 = (wave * 2 + 0) * 16 + t;
    const int wcol1 = (wave * 2 + 1) * 16 + t;
    f32x4 A0 = {0.f, 0.f, 0.f, 0.f}, A1 = {0.f, 0.f, 0.f, 0.f};
    const u16* wt0 = WT + wcol0 * 480 + q * 8;
    const u16* wt1 = WT + wcol1 * 480 + q * 8;
    #pragma unroll
    for (int ks = 0; ks < KP; ++ks) {
        const int u = ks * 4 + q;
        short8 a   = *(const short8*)&wf[t * 256 + ((u ^ (t & 7)) << 2)];
        short8 bb0 = *(const short8*)(wt0 + ks * 32);
        short8 bb1 = *(const short8*)(wt1 + ks * 32);
        A0 = __builtin_amdgcn_mfma_f32_16x16x32_bf16(a, bb0, A0, 0, 0, 0);
        A1 = __builtin_amdgcn_mfma_f32_16x16x32_bf16(a, bb1, A1, 0, 0, 0);
    }
    const int base = blockIdx.x * PPB;
    float s0 = 0.f, q0 = 0.f, s1 = 0.f, q1 = 0.f;
    #pragma unroll
    for (int r = 0; r < 4; ++r) {
        float v0 = A0[r], v1 = A1[r];
        out[(base + q * 4 + r) * COUT + wcol0] = v0;
        out[(base + q * 4 + r) * COUT + wcol1] = v1;
        s0 += v0; q0 = fmaf(v0, v0, q0);
        s1 += v1; q1 = fmaf(v1, v1, q1);
    }
    s0 += __shfl_xor(s0, 16, 64); s0 += __shfl_xor(s0, 32, 64);
    q0 += __shfl_xor(q0, 16, 64); q0 += __shfl_xor(q0, 32, 64);
    s1 += __shfl_xor(s1, 16, 64); s1 += __shfl_xor(s1, 32, 64);
    q1 += __shfl_xor(q1, 16, 64); q1 += __shfl_xor(q1, 32, 64);
    if (q == 0) {
        const int bin = blockIdx.x >> 4;
        atomicAdd(&Sp[wcol0 * NBIN + bin], s0);
        atomicAdd(&Qp[wcol0 * NBIN + bin], q0);
        atomicAdd(&Sp[wcol1 * NBIN + bin], s1);
        atomicAdd(&Qp[wcol1 * NBIN + bin], q1);
    }
}

// 64 blocks: block = channel; reduce bins -> scale/shift
__global__ __launch_bounds__(256) void bn_reduce(
    const float* __restrict__ Sp, const float* __restrict__ Qp,
    const float* __restrict__ gamma, const float* __restrict__ beta,
    float* __restrict__ scsh)
{
    const int ch = blockIdx.x;
    const int tid = threadIdx.x;
    float s = 0.f, qq = 0.f;
    if (tid < NBIN / 4) {                                // 128 threads carry data
        float4 a = ((const float4*)(Sp + ch * NBIN))[tid]; s  = a.x + a.y + a.z + a.w;
        float4 b = ((const float4*)(Qp + ch * NBIN))[tid]; qq = b.x + b.y + b.z + b.w;
    }
    #pragma unroll
    for (int off = 1; off < 64; off <<= 1) {
        s += __shfl_xor(s, off, 64); qq += __shfl_xor(qq, off, 64);
    }
    __shared__ float red[8];
    const int w = tid >> 6;
    if ((tid & 63) == 0) { red[w * 2] = s; red[w * 2 + 1] = qq; }
    __syncthreads();
    if (tid == 0) {
        s  = red[0] + red[2] + red[4] + red[6];
        qq = red[1] + red[3] + red[5] + red[7];
        float mean = s * (1.0f / NPTS);
        float var  = qq * (1.0f / NPTS) - mean * mean;
        float sc = gamma[ch] * rsqrtf(var + BN_EPS);
        scsh[ch] = sc;
        scsh[64 + ch] = beta[ch] - mean * sc;
    }
}

__global__ __launch_bounds__(256) void bn_apply(
    float* __restrict__ out, const float* __restrict__ scsh)
{
    __shared__ float sc[64], sh[64];
    const int tid = threadIdx.x;
    if (tid < 64) { sc[tid] = scsh[tid]; sh[tid] = scsh[64 + tid]; }
    __syncthreads();
    const int gid = blockIdx.x * 256 + tid;          // 4 f32 per thread
    float4 v = ((const float4*)out)[gid];
    const int c0 = (gid * 4) & 63;
    float y0 = fmaf(v.x, sc[c0 + 0], sh[c0 + 0]);
    float y1 = fmaf(v.y, sc[c0 + 1], sh[c0 + 1]);
    float y2 = fmaf(v.z, sc[c0 + 2], sh[c0 + 2]);
    float y3 = fmaf(v.w, sc[c0 + 3], sh[c0 + 3]);
    float4 w;
    w.x = fmaxf(y0, NEG_SLOPE * y0);
    w.y = fmaxf(y1, NEG_SLOPE * y1);
    w.z = fmaxf(y2, NEG_SLOPE * y2);
    w.w = fmaxf(y3, NEG_SLOPE * y3);
    ((float4*)out)[gid] = w;
}

extern "C" void kernel_launch(void* const* d_in, const int* in_sizes, int n_in,
                              void* d_out, int out_size, void* d_ws, size_t ws_size,
                              hipStream_t stream) {
    (void)in_sizes; (void)n_in; (void)out_size; (void)ws_size;
    const float* xyz   = (const float*)d_in[0];
    const float* feats = (const float*)d_in[1];
    const int*   nbr   = (const int*)d_in[2];
    const float* Wg    = (const float*)d_in[3];
    const float* kpts  = (const float*)d_in[4];
    const float* gamma = (const float*)d_in[5];
    const float* beta  = (const float*)d_in[6];
    float* out = (float*)d_out;
    char* ws = (char*)d_ws;
    u16*    WT   = (u16*)(ws + WS_WT);
    float*  scsh = (float*)(ws + WS_SCSH);
    float*  Sp   = (float*)(ws + WS_SP);
    float*  Qp   = (float*)(ws + WS_QP);
    float4* XY   = (float4*)(ws + WS_XY);
    u32*    FBu  = (u32*)(ws + WS_FB);

    prep<<<dim3(9082), dim3(256), 0, stream>>>(Wg, feats, xyz, WT, XY, FBu, Sp);
    kpconv_conv<<<dim3(NBLK), dim3(128), 0, stream>>>(xyz, nbr, XY, FBu, WT, kpts, out, Sp, Qp);
    bn_reduce<<<dim3(64), dim3(256), 0, stream>>>(Sp, Qp, gamma, beta, scsh);
    bn_apply<<<dim3((NPTS * COUT) / (256 * 4)), dim3(256), 0, stream>>>(out, scsh);
}